// Round 3
// baseline (454.953 us; speedup 1.0000x reference)
//
#include <hip/hip_runtime.h>

#define NH 8

using hfrag = __attribute__((ext_vector_type(8))) _Float16;
using f4v   = __attribute__((ext_vector_type(4))) float;

// ---------------------------------------------------------------------------
// Merged prep:
//   blocks [0,2048):    W3 (128k x 16384f f32) -> w3t (16384f x 128k fp16,
//                       pre-scaled by log2e so softmax uses raw v_exp_f32)
//   blocks [2048,3072): x -> xT
//   blocks [3072,3136): xms[n,d] = sum_{l masked} x[n,l,d], nmask[n] = #masked
// ---------------------------------------------------------------------------
__global__ __launch_bounds__(256) void prep_kernel(
    const float* __restrict__ W3, _Float16* __restrict__ w3t,
    const float* __restrict__ x, float* __restrict__ xT,
    const float* __restrict__ maskx, float* __restrict__ xms,
    float* __restrict__ nmask) {
  __shared__ float t[32][33];
  __shared__ float sm2[2][128];
  const int bid = blockIdx.x;
  const int tx = threadIdx.x & 31, ty = threadIdx.x >> 5;  // ty 0..7
  if (bid < 2048) {
    const int f0 = (bid & 511) * 32;
    const int k0 = (bid >> 9) * 32;
#pragma unroll
    for (int i = 0; i < 4; ++i)
      t[ty + 8 * i][tx] = W3[(size_t)(k0 + ty + 8 * i) * 16384 + f0 + tx];
    __syncthreads();
#pragma unroll
    for (int i = 0; i < 4; ++i)
      w3t[(size_t)(f0 + ty + 8 * i) * 128 + k0 + tx] =
          (_Float16)(t[tx][ty + 8 * i] * 1.44269504f);
  } else if (bid < 3072) {
    const int b2 = bid - 2048;
    const int d0 = (b2 & 3) * 32, l0 = ((b2 >> 2) & 3) * 32, n = b2 >> 4;
    const size_t base = (size_t)n * 16384;
#pragma unroll
    for (int i = 0; i < 4; ++i)
      t[ty + 8 * i][tx] = x[base + (size_t)(l0 + ty + 8 * i) * 128 + d0 + tx];
    __syncthreads();
#pragma unroll
    for (int i = 0; i < 4; ++i)
      xT[base + (size_t)(d0 + ty + 8 * i) * 128 + l0 + tx] = t[tx][ty + 8 * i];
  } else {
    const int n = bid - 3072;
    const int d = threadIdx.x & 127, seg = threadIdx.x >> 7;
    const float* xn = x + (size_t)n * 16384;
    const float* mn = maskx + n * 128;
    float acc = 0.f;
#pragma unroll 8
    for (int l = seg * 64; l < seg * 64 + 64; ++l)
      acc += (mn[l] == 0.f) ? xn[l * 128 + d] : 0.f;
    sm2[seg][d] = acc;
    __syncthreads();
    if (threadIdx.x < 128) xms[n * 128 + d] = sm2[0][d] + sm2[1][d];
    if (threadIdx.x == 0) {
      float c = 0.f;
      for (int l = 0; l < 128; ++l) c += (mn[l] == 0.f) ? 1.f : 0.f;
      nmask[n] = c;
    }
  }
}

// ---------------------------------------------------------------------------
// MLP: h2 = relu(relu(x@W1+b1)@W2+b2) * mask -> fp16. Masked l-rows are
// zeroed here so the fused kernel needs no per-element mask logic.
// grid (64 n, 4 lq), 256 thr.
// ---------------------------------------------------------------------------
__global__ __launch_bounds__(256) void mlp2_kernel(
    const float* __restrict__ x, const float* __restrict__ W1,
    const float* __restrict__ b1, const float* __restrict__ W2,
    const float* __restrict__ b2, const float* __restrict__ maskx,
    _Float16* __restrict__ h2f) {
  __shared__ float wbuf[128 * 128];   // 64 KB weights
  __shared__ float abuf[32 * 132];    // padded activations
  const int n = blockIdx.x, lq = blockIdx.y;
  const int tid = threadIdx.x;

  {
    const float4* wsrc = (const float4*)W1;
    float4* wdst = (float4*)wbuf;
#pragma unroll
    for (int i = 0; i < 16; ++i) wdst[tid + 256 * i] = wsrc[tid + 256 * i];
    const float4* xsrc = (const float4*)(x + (size_t)n * 16384 + lq * 32 * 128);
#pragma unroll
    for (int i = 0; i < 4; ++i) {
      int idx = tid + 256 * i;
      int row = idx >> 5, c4 = idx & 31;
      *(float4*)&abuf[row * 132 + c4 * 4] = xsrc[idx];
    }
  }
  __syncthreads();

  const int tl = tid >> 4, td = tid & 15;
  const int r0 = tl * 2, j0 = td * 8;
  const float m0 = maskx[n * 128 + lq * 32 + r0 + 0];
  const float m1 = maskx[n * 128 + lq * 32 + r0 + 1];
  float s[2][8];

#pragma unroll
  for (int i = 0; i < 2; ++i)
#pragma unroll
    for (int j = 0; j < 8; ++j) s[i][j] = 0.f;
#pragma unroll 4
  for (int k = 0; k < 128; ++k) {
    float a0 = abuf[(r0 + 0) * 132 + k];
    float a1 = abuf[(r0 + 1) * 132 + k];
    float4 bv0 = *(const float4*)&wbuf[k * 128 + j0];
    float4 bv1 = *(const float4*)&wbuf[k * 128 + j0 + 4];
    float b[8] = {bv0.x, bv0.y, bv0.z, bv0.w, bv1.x, bv1.y, bv1.z, bv1.w};
#pragma unroll
    for (int j = 0; j < 8; ++j) {
      s[0][j] += a0 * b[j];
      s[1][j] += a1 * b[j];
    }
  }
  __syncthreads();

#pragma unroll
  for (int i = 0; i < 2; ++i)
#pragma unroll
    for (int j = 0; j < 8; ++j)
      abuf[(r0 + i) * 132 + j0 + j] = fmaxf(s[i][j] + b1[j0 + j], 0.f);
  {
    const float4* wsrc = (const float4*)W2;
    float4* wdst = (float4*)wbuf;
#pragma unroll
    for (int i = 0; i < 16; ++i) wdst[tid + 256 * i] = wsrc[tid + 256 * i];
  }
  __syncthreads();

#pragma unroll
  for (int i = 0; i < 2; ++i)
#pragma unroll
    for (int j = 0; j < 8; ++j) s[i][j] = 0.f;
#pragma unroll 4
  for (int k = 0; k < 128; ++k) {
    float a0 = abuf[(r0 + 0) * 132 + k];
    float a1 = abuf[(r0 + 1) * 132 + k];
    float4 bv0 = *(const float4*)&wbuf[k * 128 + j0];
    float4 bv1 = *(const float4*)&wbuf[k * 128 + j0 + 4];
    float b[8] = {bv0.x, bv0.y, bv0.z, bv0.w, bv1.x, bv1.y, bv1.z, bv1.w};
#pragma unroll
    for (int j = 0; j < 8; ++j) {
      s[0][j] += a0 * b[j];
      s[1][j] += a1 * b[j];
    }
  }

  const float mm[2] = {m0, m1};
  const size_t obase = (size_t)n * 16384 + (size_t)(lq * 32) * 128;
#pragma unroll
  for (int i = 0; i < 2; ++i)
#pragma unroll
    for (int j = 0; j < 8; ++j)
      h2f[obase + (size_t)(r0 + i) * 128 + j0 + j] =
          (_Float16)(fmaxf(s[i][j] + b2[j0 + j], 0.f) * mm[i]);
}

// ---------------------------------------------------------------------------
// Fused: 512 thr, 8 waves x 16-col strips, 8 h per block. Full A tile in
// registers (128 VGPR); __launch_bounds__(512,8) caps at 256 VGPR so nothing
// spills (live set ~230). Mask handled algebraically: masked rows of h2 are
// zero -> exp2(0)=1 -> subtract nmask from den and xms[d] from num.
// grid (64 n, 16 hg).
// ---------------------------------------------------------------------------
__global__ __launch_bounds__(512, 8) void fused_mfma_kernel(
    const _Float16* __restrict__ h2f, const _Float16* __restrict__ w3t,
    const float* __restrict__ xT, const float* __restrict__ xms,
    const float* __restrict__ nmask, const float* __restrict__ tbias,
    float* __restrict__ out) {
  __shared__ _Float16 aLDS[128 * 128];   // 32 KB, slot-swizzled
  __shared__ float wLDS[8][NH][16];      // per-wave per-h per-col pc
  const int n = blockIdx.x, hg = blockIdx.y;
  const int tid = threadIdx.x;
  const int wid = tid >> 6, lane = tid & 63;
  const int r = lane & 15, kg = lane >> 4;

  // stage h2[n] (fp16, 32 KB) into LDS, swizzling 16B slots: dsl = sl^(row&7)
  const _Float16* h2n = h2f + (size_t)n * 16384;
  {
    char* lb = (char*)aLDS;
#pragma unroll
    for (int i = 0; i < 4; ++i) {
      const int og = (tid + 512 * i) * 16;  // linear global byte offset
      const int row = og >> 8;              // 256 B per row (128 fp16)
      const int sl = (og >> 4) & 15;        // 16B slot in row
      const float4 v = *(const float4*)((const char*)h2n + og);
      *(float4*)(lb + row * 256 + (sl ^ (row & 7)) * 16) = v;
    }
  }

  // this lane's x column (d = wid*16 + r), reused across all 8 h
  f4v xv[8];
  {
    const float* xc =
        xT + (size_t)n * 16384 + (size_t)(wid * 16 + r) * 128 + kg * 4;
#pragma unroll
    for (int rt = 0; rt < 8; ++rt) xv[rt] = *(const f4v*)(xc + rt * 16);
  }
  const float xm = xms[n * 128 + wid * 16 + r];  // masked-row x sum, this col
  const float nm = nmask[n];                     // masked-row count

  __syncthreads();

  // hoist the full A tile (128x128 fp16) into registers: 32 frags, 128 VGPRs
  hfrag af[4][8];
  {
    const char* lb = (const char*)aLDS;
#pragma unroll
    for (int ks = 0; ks < 4; ++ks) {
      const int dslByte = ((ks * 4 + kg) ^ (r & 7)) * 16;
#pragma unroll
      for (int rt = 0; rt < 8; ++rt)
        af[ks][rt] = *(const hfrag*)(lb + (rt * 16 + r) * 256 + dslByte);
    }
  }

  // B fragments for h=0; per-h stride is 128*128 fp16
  const _Float16* w3g =
      w3t + ((size_t)(hg * NH) * 128 + wid * 16 + r) * 128 + kg * 8;
  hfrag bcur[4];
#pragma unroll
  for (int ks = 0; ks < 4; ++ks) bcur[ks] = *(const hfrag*)(w3g + ks * 32);

#pragma unroll
  for (int h = 0; h < NH; ++h) {
    // GEMM: 32 MFMAs, zero C-init
    f4v acc[8];
#pragma unroll
    for (int rt = 0; rt < 8; ++rt) {
      f4v z = {0.f, 0.f, 0.f, 0.f};
      acc[rt] = __builtin_amdgcn_mfma_f32_16x16x32_f16(af[0][rt], bcur[0], z,
                                                       0, 0, 0);
    }
#pragma unroll
    for (int ks = 1; ks < 4; ++ks)
#pragma unroll
      for (int rt = 0; rt < 8; ++rt)
        acc[rt] = __builtin_amdgcn_mfma_f32_16x16x32_f16(af[ks][rt], bcur[ks],
                                                         acc[rt], 0, 0, 0);

    // prefetch next h's B into bcur (WAR after last MFMA read); softmax
    // below hides the load latency
    if (h + 1 < NH) {
      const _Float16* w3n = w3g + (size_t)(h + 1) * 16384;
#pragma unroll
      for (int ks = 0; ks < 4; ++ks) bcur[ks] = *(const hfrag*)(w3n + ks * 32);
    }

    // softmax over l + contraction with x. Logits pre-scaled by log2e and
    // O(1) -> raw exp2 safe. Masked rows contribute exactly 1 to den and
    // x[l,d] to num; corrected by nm / xm after the reduction.
    float den0 = 0.f, den1 = 0.f, num0 = 0.f, num1 = 0.f;
#pragma unroll
    for (int rt = 0; rt < 8; rt += 2) {
#pragma unroll
      for (int j = 0; j < 4; ++j) {
        float e0 = __builtin_amdgcn_exp2f(acc[rt][j]);
        float e1 = __builtin_amdgcn_exp2f(acc[rt + 1][j]);
        den0 += e0;
        num0 += e0 * xv[rt][j];
        den1 += e1;
        num1 += e1 * xv[rt + 1][j];
      }
    }
    float den = den0 + den1, num = num0 + num1;
    den += __shfl_xor(den, 16);
    den += __shfl_xor(den, 32);
    num += __shfl_xor(num, 16);
    num += __shfl_xor(num, 32);
    den -= nm;
    num -= xm;
    if (kg == 0) wLDS[wid][h][r] = num * __builtin_amdgcn_rcpf(den);
  }

  __syncthreads();
  // final reduce: 128 threads; thread (h = tid>>4, r = tid&15) sums 8 waves,
  // then 16 r-lanes fold via shfl (stays inside a 16-lane group).
  if (tid < 128) {
    const int rr = tid & 15, hh = tid >> 4;
    float s = 0.f;
#pragma unroll
    for (int w = 0; w < 8; ++w) s += wLDS[w][hh][rr];
    s += __shfl_xor(s, 1);
    s += __shfl_xor(s, 2);
    s += __shfl_xor(s, 4);
    s += __shfl_xor(s, 8);
    if (rr == 0) {
      const int h = hg * NH + hh;
      out[n * 128 + h] = fmaxf(s + tbias[h], 0.f);
    }
  }
}

// ---------------------------------------------------------------------------
extern "C" void kernel_launch(void* const* d_in, const int* in_sizes, int n_in,
                              void* d_out, int out_size, void* d_ws,
                              size_t ws_size, hipStream_t stream) {
  (void)in_sizes; (void)n_in; (void)out_size; (void)ws_size;
  const float* x     = (const float*)d_in[0];
  const float* maskx = (const float*)d_in[1];
  const float* W1    = (const float*)d_in[2];
  const float* b1    = (const float*)d_in[3];
  const float* W2    = (const float*)d_in[4];
  const float* b2    = (const float*)d_in[5];
  const float* W3    = (const float*)d_in[6];
  // d_in[7] = b3: constant along the softmax (L) axis -> cancels, unused.
  const float* tbias = (const float*)d_in[8];
  float* out = (float*)d_out;

  char* ws = (char*)d_ws;
  _Float16* w3t   = (_Float16*)ws;                          // 4 MB @ 0
  _Float16* h2f   = (_Float16*)(ws + (4u << 20));           // 2 MB @ 4M
  float*    xms   = (float*)(ws + (6u << 20));              // 32 KB @ 6M
  float*    nmask = (float*)(ws + (6u << 20) + (64u << 10));// 256 B
  float*    xT    = (float*)(ws + (8u << 20));              // 4 MB @ 8M

  prep_kernel<<<3136, 256, 0, stream>>>(W3, w3t, x, xT, maskx, xms, nmask);
  mlp2_kernel<<<dim3(64, 4), 256, 0, stream>>>(x, W1, b1, W2, b2, maskx, h2f);
  fused_mfma_kernel<<<dim3(64, 16), 512, 0, stream>>>(h2f, w3t, xT, xms,
                                                      nmask, tbias, out);
}

// Round 4
// 74.755 us; speedup vs baseline: 6.0859x; 6.0859x over previous
//
#include <hip/hip_runtime.h>

#define NH 16

using hfrag = __attribute__((ext_vector_type(8))) _Float16;
using f4v   = __attribute__((ext_vector_type(4))) float;

// ---------------------------------------------------------------------------
// Merged prep:
//   blocks [0,2048):    W3 (128k x 16384f f32) -> w3t (16384f x 128k fp16,
//                       pre-scaled by log2e so softmax uses raw v_exp_f32)
//   blocks [2048,3072): x -> xT
//   blocks [3072,3136): xms[n,d] = sum_{l masked} x[n,l,d], nmask[n] = #masked
// ---------------------------------------------------------------------------
__global__ __launch_bounds__(256) void prep_kernel(
    const float* __restrict__ W3, _Float16* __restrict__ w3t,
    const float* __restrict__ x, float* __restrict__ xT,
    const float* __restrict__ maskx, float* __restrict__ xms,
    float* __restrict__ nmask) {
  __shared__ float t[32][33];
  __shared__ float sm2[2][128];
  const int bid = blockIdx.x;
  const int tx = threadIdx.x & 31, ty = threadIdx.x >> 5;  // ty 0..7
  if (bid < 2048) {
    const int f0 = (bid & 511) * 32;
    const int k0 = (bid >> 9) * 32;
#pragma unroll
    for (int i = 0; i < 4; ++i)
      t[ty + 8 * i][tx] = W3[(size_t)(k0 + ty + 8 * i) * 16384 + f0 + tx];
    __syncthreads();
#pragma unroll
    for (int i = 0; i < 4; ++i)
      w3t[(size_t)(f0 + ty + 8 * i) * 128 + k0 + tx] =
          (_Float16)(t[tx][ty + 8 * i] * 1.44269504f);
  } else if (bid < 3072) {
    const int b2 = bid - 2048;
    const int d0 = (b2 & 3) * 32, l0 = ((b2 >> 2) & 3) * 32, n = b2 >> 4;
    const size_t base = (size_t)n * 16384;
#pragma unroll
    for (int i = 0; i < 4; ++i)
      t[ty + 8 * i][tx] = x[base + (size_t)(l0 + ty + 8 * i) * 128 + d0 + tx];
    __syncthreads();
#pragma unroll
    for (int i = 0; i < 4; ++i)
      xT[base + (size_t)(d0 + ty + 8 * i) * 128 + l0 + tx] = t[tx][ty + 8 * i];
  } else {
    const int n = bid - 3072;
    const int d = threadIdx.x & 127, seg = threadIdx.x >> 7;
    const float* xn = x + (size_t)n * 16384;
    const float* mn = maskx + n * 128;
    float acc = 0.f;
#pragma unroll 8
    for (int l = seg * 64; l < seg * 64 + 64; ++l)
      acc += (mn[l] == 0.f) ? xn[l * 128 + d] : 0.f;
    sm2[seg][d] = acc;
    __syncthreads();
    if (threadIdx.x < 128) xms[n * 128 + d] = sm2[0][d] + sm2[1][d];
    if (threadIdx.x == 0) {
      float c = 0.f;
      for (int l = 0; l < 128; ++l) c += (mn[l] == 0.f) ? 1.f : 0.f;
      nmask[n] = c;
    }
  }
}

// ---------------------------------------------------------------------------
// MLP: h2 = relu(relu(x@W1+b1)@W2+b2) * mask -> fp16. Masked l-rows are
// zeroed here so the fused kernel needs no per-element mask logic.
// grid (64 n, 4 lq), 256 thr.
// ---------------------------------------------------------------------------
__global__ __launch_bounds__(256) void mlp2_kernel(
    const float* __restrict__ x, const float* __restrict__ W1,
    const float* __restrict__ b1, const float* __restrict__ W2,
    const float* __restrict__ b2, const float* __restrict__ maskx,
    _Float16* __restrict__ h2f) {
  __shared__ float wbuf[128 * 128];   // 64 KB weights
  __shared__ float abuf[32 * 132];    // padded activations
  const int n = blockIdx.x, lq = blockIdx.y;
  const int tid = threadIdx.x;

  {
    const float4* wsrc = (const float4*)W1;
    float4* wdst = (float4*)wbuf;
#pragma unroll
    for (int i = 0; i < 16; ++i) wdst[tid + 256 * i] = wsrc[tid + 256 * i];
    const float4* xsrc = (const float4*)(x + (size_t)n * 16384 + lq * 32 * 128);
#pragma unroll
    for (int i = 0; i < 4; ++i) {
      int idx = tid + 256 * i;
      int row = idx >> 5, c4 = idx & 31;
      *(float4*)&abuf[row * 132 + c4 * 4] = xsrc[idx];
    }
  }
  __syncthreads();

  const int tl = tid >> 4, td = tid & 15;
  const int r0 = tl * 2, j0 = td * 8;
  const float m0 = maskx[n * 128 + lq * 32 + r0 + 0];
  const float m1 = maskx[n * 128 + lq * 32 + r0 + 1];
  float s[2][8];

#pragma unroll
  for (int i = 0; i < 2; ++i)
#pragma unroll
    for (int j = 0; j < 8; ++j) s[i][j] = 0.f;
#pragma unroll 4
  for (int k = 0; k < 128; ++k) {
    float a0 = abuf[(r0 + 0) * 132 + k];
    float a1 = abuf[(r0 + 1) * 132 + k];
    float4 bv0 = *(const float4*)&wbuf[k * 128 + j0];
    float4 bv1 = *(const float4*)&wbuf[k * 128 + j0 + 4];
    float b[8] = {bv0.x, bv0.y, bv0.z, bv0.w, bv1.x, bv1.y, bv1.z, bv1.w};
#pragma unroll
    for (int j = 0; j < 8; ++j) {
      s[0][j] += a0 * b[j];
      s[1][j] += a1 * b[j];
    }
  }
  __syncthreads();

#pragma unroll
  for (int i = 0; i < 2; ++i)
#pragma unroll
    for (int j = 0; j < 8; ++j)
      abuf[(r0 + i) * 132 + j0 + j] = fmaxf(s[i][j] + b1[j0 + j], 0.f);
  {
    const float4* wsrc = (const float4*)W2;
    float4* wdst = (float4*)wbuf;
#pragma unroll
    for (int i = 0; i < 16; ++i) wdst[tid + 256 * i] = wsrc[tid + 256 * i];
  }
  __syncthreads();

#pragma unroll
  for (int i = 0; i < 2; ++i)
#pragma unroll
    for (int j = 0; j < 8; ++j) s[i][j] = 0.f;
#pragma unroll 4
  for (int k = 0; k < 128; ++k) {
    float a0 = abuf[(r0 + 0) * 132 + k];
    float a1 = abuf[(r0 + 1) * 132 + k];
    float4 bv0 = *(const float4*)&wbuf[k * 128 + j0];
    float4 bv1 = *(const float4*)&wbuf[k * 128 + j0 + 4];
    float b[8] = {bv0.x, bv0.y, bv0.z, bv0.w, bv1.x, bv1.y, bv1.z, bv1.w};
#pragma unroll
    for (int j = 0; j < 8; ++j) {
      s[0][j] += a0 * b[j];
      s[1][j] += a1 * b[j];
    }
  }

  const float mm[2] = {m0, m1};
  const size_t obase = (size_t)n * 16384 + (size_t)(lq * 32) * 128;
#pragma unroll
  for (int i = 0; i < 2; ++i)
#pragma unroll
    for (int j = 0; j < 8; ++j)
      h2f[obase + (size_t)(r0 + i) * 128 + j0 + j] =
          (_Float16)(fmaxf(s[i][j] + b2[j0 + j], 0.f) * mm[i]);
}

// ---------------------------------------------------------------------------
// Fused: 512 thr, 8 waves x 16-col strips, 16 h per block. Full A tile in
// registers (128 VGPR). __launch_bounds__(512,2): 2 waves/SIMD -> 256-VGPR
// cap, 1 block/CU (live set ~230, no spill). Mask handled algebraically:
// masked rows of h2 are zero -> exp2(0)=1 -> subtract nmask from den and
// xms[d] from num. h-loop kept rolled (unroll 2) for I-cache. grid (64, 8).
// ---------------------------------------------------------------------------
__global__ __launch_bounds__(512, 2) void fused_mfma_kernel(
    const _Float16* __restrict__ h2f, const _Float16* __restrict__ w3t,
    const float* __restrict__ xT, const float* __restrict__ xms,
    const float* __restrict__ nmask, const float* __restrict__ tbias,
    float* __restrict__ out) {
  __shared__ _Float16 aLDS[128 * 128];   // 32 KB, slot-swizzled
  __shared__ float wLDS[8][NH][16];      // per-wave per-h per-col pc (8 KB)
  const int n = blockIdx.x, hg = blockIdx.y;
  const int tid = threadIdx.x;
  const int wid = tid >> 6, lane = tid & 63;
  const int r = lane & 15, kg = lane >> 4;

  // stage h2[n] (fp16, 32 KB) into LDS, swizzling 16B slots: dsl = sl^(row&7)
  const _Float16* h2n = h2f + (size_t)n * 16384;
  {
    char* lb = (char*)aLDS;
#pragma unroll
    for (int i = 0; i < 4; ++i) {
      const int og = (tid + 512 * i) * 16;  // linear global byte offset
      const int row = og >> 8;              // 256 B per row (128 fp16)
      const int sl = (og >> 4) & 15;        // 16B slot in row
      const float4 v = *(const float4*)((const char*)h2n + og);
      *(float4*)(lb + row * 256 + (sl ^ (row & 7)) * 16) = v;
    }
  }

  // this lane's x column (d = wid*16 + r), reused across all h
  f4v xv[8];
  {
    const float* xc =
        xT + (size_t)n * 16384 + (size_t)(wid * 16 + r) * 128 + kg * 4;
#pragma unroll
    for (int rt = 0; rt < 8; ++rt) xv[rt] = *(const f4v*)(xc + rt * 16);
  }
  const float xm = xms[n * 128 + wid * 16 + r];  // masked-row x sum, this col
  const float nm = nmask[n];                     // masked-row count

  __syncthreads();

  // hoist the full A tile (128x128 fp16) into registers: 32 frags, 128 VGPRs
  hfrag af[4][8];
  {
    const char* lb = (const char*)aLDS;
#pragma unroll
    for (int ks = 0; ks < 4; ++ks) {
      const int dslByte = ((ks * 4 + kg) ^ (r & 7)) * 16;
#pragma unroll
      for (int rt = 0; rt < 8; ++rt)
        af[ks][rt] = *(const hfrag*)(lb + (rt * 16 + r) * 256 + dslByte);
    }
  }

  // B fragments for h=0; per-h stride is 128*128 fp16
  const _Float16* w3g =
      w3t + ((size_t)(hg * NH) * 128 + wid * 16 + r) * 128 + kg * 8;
  hfrag bcur[4];
#pragma unroll
  for (int ks = 0; ks < 4; ++ks) bcur[ks] = *(const hfrag*)(w3g + ks * 32);

#pragma unroll 2
  for (int h = 0; h < NH; ++h) {
    // GEMM: 32 MFMAs, zero C-init
    f4v acc[8];
#pragma unroll
    for (int rt = 0; rt < 8; ++rt) {
      f4v z = {0.f, 0.f, 0.f, 0.f};
      acc[rt] = __builtin_amdgcn_mfma_f32_16x16x32_f16(af[0][rt], bcur[0], z,
                                                       0, 0, 0);
    }
#pragma unroll
    for (int ks = 1; ks < 4; ++ks)
#pragma unroll
      for (int rt = 0; rt < 8; ++rt)
        acc[rt] = __builtin_amdgcn_mfma_f32_16x16x32_f16(af[ks][rt], bcur[ks],
                                                         acc[rt], 0, 0, 0);

    // prefetch next h's B into bcur (WAR after last MFMA read); softmax
    // below hides the load latency
    if (h + 1 < NH) {
      const _Float16* w3n = w3g + (size_t)(h + 1) * 16384;
#pragma unroll
      for (int ks = 0; ks < 4; ++ks) bcur[ks] = *(const hfrag*)(w3n + ks * 32);
    }

    // softmax over l + contraction with x. Logits pre-scaled by log2e and
    // O(1) -> raw exp2 safe. Masked rows contribute exactly 1 to den and
    // x[l,d] to num; corrected by nm / xm after the reduction.
    float den0 = 0.f, den1 = 0.f, num0 = 0.f, num1 = 0.f;
#pragma unroll
    for (int rt = 0; rt < 8; rt += 2) {
#pragma unroll
      for (int j = 0; j < 4; ++j) {
        float e0 = __builtin_amdgcn_exp2f(acc[rt][j]);
        float e1 = __builtin_amdgcn_exp2f(acc[rt + 1][j]);
        den0 += e0;
        num0 += e0 * xv[rt][j];
        den1 += e1;
        num1 += e1 * xv[rt + 1][j];
      }
    }
    float den = den0 + den1, num = num0 + num1;
    den += __shfl_xor(den, 16);
    den += __shfl_xor(den, 32);
    num += __shfl_xor(num, 16);
    num += __shfl_xor(num, 32);
    den -= nm;
    num -= xm;
    if (kg == 0) wLDS[wid][h][r] = num * __builtin_amdgcn_rcpf(den);
  }

  __syncthreads();
  // final reduce: 256 threads; thread (h = tid>>4, r = tid&15) sums 8 waves,
  // then 16 r-lanes fold via shfl (stays inside a 16-lane group).
  if (tid < 256) {
    const int rr = tid & 15, hh = tid >> 4;
    float s = 0.f;
#pragma unroll
    for (int w = 0; w < 8; ++w) s += wLDS[w][hh][rr];
    s += __shfl_xor(s, 1);
    s += __shfl_xor(s, 2);
    s += __shfl_xor(s, 4);
    s += __shfl_xor(s, 8);
    if (rr == 0) {
      const int h = hg * NH + hh;
      out[n * 128 + h] = fmaxf(s + tbias[h], 0.f);
    }
  }
}

// ---------------------------------------------------------------------------
extern "C" void kernel_launch(void* const* d_in, const int* in_sizes, int n_in,
                              void* d_out, int out_size, void* d_ws,
                              size_t ws_size, hipStream_t stream) {
  (void)in_sizes; (void)n_in; (void)out_size; (void)ws_size;
  const float* x     = (const float*)d_in[0];
  const float* maskx = (const float*)d_in[1];
  const float* W1    = (const float*)d_in[2];
  const float* b1    = (const float*)d_in[3];
  const float* W2    = (const float*)d_in[4];
  const float* b2    = (const float*)d_in[5];
  const float* W3    = (const float*)d_in[6];
  // d_in[7] = b3: constant along the softmax (L) axis -> cancels, unused.
  const float* tbias = (const float*)d_in[8];
  float* out = (float*)d_out;

  char* ws = (char*)d_ws;
  _Float16* w3t   = (_Float16*)ws;                          // 4 MB @ 0
  _Float16* h2f   = (_Float16*)(ws + (4u << 20));           // 2 MB @ 4M
  float*    xms   = (float*)(ws + (6u << 20));              // 32 KB @ 6M
  float*    nmask = (float*)(ws + (6u << 20) + (64u << 10));// 256 B
  float*    xT    = (float*)(ws + (8u << 20));              // 4 MB @ 8M

  prep_kernel<<<3136, 256, 0, stream>>>(W3, w3t, x, xT, maskx, xms, nmask);
  mlp2_kernel<<<dim3(64, 4), 256, 0, stream>>>(x, W1, b1, W2, b2, maskx, h2f);
  fused_mfma_kernel<<<dim3(64, 8), 512, 0, stream>>>(h2f, w3t, xT, xms,
                                                     nmask, tbias, out);
}